// Round 10
// baseline (62.544 us; speedup 1.0000x reference)
//
#include <hip/hip_runtime.h>

// AdaptiveVectorQuantizer on MI355X (gfx950) — split-kernel structure.
// ROUND-10 MEASUREMENT PROBE: avq_expand launched TWICE (idempotent,
// deterministic). With r5 (A+B=40.02) and r8 (2A+B=52.96 -> t_A+gap=12.96),
// this yields t_B+gap = dur - 40.02, completing the per-kernel attribution.
// Kernels bit-identical to round 5 (the 40.0us best).
// A (avq_assign): 1 thread/position, reg-staged 64 channel loads, LDS cb.
// B (avq_expand): streaming expand, one (l,n,c) slab per block, codebook
//   column in LDS, 4x16B nontemporal stores/thread. Block 0 = loss finalize.

namespace {

typedef float f32x4 __attribute__((ext_vector_type(4)));

constexpr int D      = 64;
constexpr int P      = 16;
constexpr int NLEV   = 4;
constexpr int NPOS   = 32 * 4096;               // 131072 positions
constexpr int ABLK   = 64;                      // 1 wave per A-block
constexpr int NBLK_A = NPOS / ABLK;             // 2048
constexpr int BBLK   = 256;
constexpr int QPT    = 4;                       // float4-quads per B-thread
constexpr int NQUAD  = NLEV * NPOS * (D / 4);   // 8,388,608
constexpr int NBLK_B = NQUAD / (BBLK * QPT);    // 8192

// ---------------- Kernel A: assignment + loss partials ----------------
__global__ __launch_bounds__(ABLK) void avq_assign(
    const float* __restrict__ in, const float* __restrict__ cb,
    float* __restrict__ partial, unsigned char* __restrict__ idx8)
{
  __shared__ f32x4 cb4_s[P][D / 4];   // reads are wave-broadcasts
  __shared__ float cb2_s[P];

  const int tid = threadIdx.x;
  for (int i = tid; i < P * (D / 4); i += ABLK)
    cb4_s[i >> 4][i & 15] = ((const f32x4*)cb)[i];
  __syncthreads();
  if (tid < P) {
    float s = 0.f;
    #pragma unroll
    for (int j = 0; j < D / 4; ++j) {
      const f32x4 v = cb4_s[tid][j];
      s = fmaf(v.x, v.x, s); s = fmaf(v.y, v.y, s);
      s = fmaf(v.z, v.z, s); s = fmaf(v.w, v.w, s);
    }
    cb2_s[tid] = s;
  }
  __syncthreads();

  const int p  = blockIdx.x * ABLK + tid;
  const int n  = p >> 12;
  const int hw = p & 4095;
  const float* __restrict__ src = in + (n << 18) + hw;   // stride 4096 over c

  // Stage all channel values first: 64 independent global loads in flight.
  float xv[D];
  #pragma unroll
  for (int c = 0; c < D; ++c) xv[c] = src[c << 12];

  float x2 = 0.f;
  #pragma unroll
  for (int c = 0; c < D; ++c) x2 = fmaf(xv[c], xv[c], x2);

  float dot[P];
  #pragma unroll
  for (int q = 0; q < P; ++q) dot[q] = 0.f;

  // Accumulation strictly c-ascending per q (numerics fixed since round 4).
  #pragma unroll
  for (int c4 = 0; c4 < D / 4; ++c4) {
    #pragma unroll
    for (int q = 0; q < P; ++q) {
      const f32x4 cv = cb4_s[q][c4];
      float dq = dot[q];
      dq = fmaf(xv[c4 * 4 + 0], cv.x, dq);
      dq = fmaf(xv[c4 * 4 + 1], cv.y, dq);
      dq = fmaf(xv[c4 * 4 + 2], cv.z, dq);
      dq = fmaf(xv[c4 * 4 + 3], cv.w, dq);
      dot[q] = dq;
    }
  }

  // rel = cb^2 - 2*dot ; x2 is a common per-row offset -> drop for argmin.
  float rel[P];
  #pragma unroll
  for (int q = 0; q < P; ++q) rel[q] = fmaf(-2.f, dot[q], cb2_s[q]);

  // Prefix argmins over nv={2,4,8,16}; strict < = jnp.argmin tie-break.
  float err[NLEV];
  {
    int bi = 0; float bv = rel[0];
    if (rel[1] < bv) { bv = rel[1]; bi = 1; }
    idx8[0 * NPOS + p] = (unsigned char)bi; err[0] = x2 + bv;
    #pragma unroll
    for (int q = 2; q < 4; ++q)  if (rel[q] < bv) { bv = rel[q]; bi = q; }
    idx8[1 * NPOS + p] = (unsigned char)bi; err[1] = x2 + bv;
    #pragma unroll
    for (int q = 4; q < 8; ++q)  if (rel[q] < bv) { bv = rel[q]; bi = q; }
    idx8[2 * NPOS + p] = (unsigned char)bi; err[2] = x2 + bv;
    #pragma unroll
    for (int q = 8; q < 16; ++q) if (rel[q] < bv) { bv = rel[q]; bi = q; }
    idx8[3 * NPOS + p] = (unsigned char)bi; err[3] = x2 + bv;
  }

  // Single-wave block: shuffle-reduce, lane 0 writes the 4 partials.
  #pragma unroll
  for (int l = 0; l < NLEV; ++l) {
    float v = err[l];
    #pragma unroll
    for (int off = 32; off > 0; off >>= 1) v += __shfl_down(v, off, 64);
    if (tid == 0) partial[blockIdx.x * NLEV + l] = v;
  }
}

// ---------------- Kernel B: expand + (block 0) finalize ----------------
__device__ inline float block_sum256(float v, float* sbuf, int tid) {
  #pragma unroll
  for (int off = 32; off > 0; off >>= 1) v += __shfl_down(v, off, 64);
  __syncthreads();
  if ((tid & 63) == 0) sbuf[tid >> 6] = v;
  __syncthreads();
  const float r = sbuf[0] + sbuf[1] + sbuf[2] + sbuf[3];
  __syncthreads();
  return r;
}

__global__ __launch_bounds__(BBLK) void avq_expand(
    const float* __restrict__ cb, const float* __restrict__ prev,
    const float* __restrict__ partial, const unsigned char* __restrict__ idx8,
    float* __restrict__ out)
{
  __shared__ float col_s[P];
  __shared__ float sbuf[4];
  const int tid = threadIdx.x;

  if (blockIdx.x == 0) {
    // ---- finalize: losses + codebook passthrough ----
    float* __restrict__ losses = out + NQUAD * 4;      // 33,554,432
    float* __restrict__ cbout  = losses + NLEV;
    for (int i = tid; i < P * D; i += BBLK) cbout[i] = cb[i];

    float s0 = 0.f, s1 = 0.f, s2 = 0.f, s3 = 0.f;
    for (int b = tid; b < NBLK_A; b += BBLK) {
      s0 += partial[b * NLEV + 0];
      s1 += partial[b * NLEV + 1];
      s2 += partial[b * NLEV + 2];
      s3 += partial[b * NLEV + 3];
    }
    float p1 = 0.f, p2 = 0.f, p3 = 0.f;
    for (int e = tid; e < 8 * D; e += BBLK) {
      const float dlt = prev[e] - cb[e];
      const float d2  = dlt * dlt;
      const int   r   = e >> 6;
      if (r < 2) p1 += d2;
      if (r < 4) p2 += d2;
      p3 += d2;
    }
    s0 = block_sum256(s0, sbuf, tid);
    s1 = block_sum256(s1, sbuf, tid);
    s2 = block_sum256(s2, sbuf, tid);
    s3 = block_sum256(s3, sbuf, tid);
    p1 = block_sum256(p1, sbuf, tid);
    p2 = block_sum256(p2, sbuf, tid);
    p3 = block_sum256(p3, sbuf, tid);
    if (tid == 0) {
      const float inv = 1.0f / 8388608.0f;             // 1/(M*D)
      const float ql0 = s0 * inv, ql1 = s1 * inv, ql2 = s2 * inv, ql3 = s3 * inv;
      losses[0] = ql0 + 0.1f * ql0;
      losses[1] = ql1 + 0.1f * ql1 + 1.0f * 0.33f * (p1 * (1.0f / 128.0f));
      losses[2] = ql2 + 2.0f * 0.33f * (p2 * (1.0f / 256.0f));
      losses[3] = ql3 + 3.0f * 0.33f * (p3 * (1.0f / 512.0f));
    }
    return;
  }

  // ---- expansion: block b covers one (l,n,c) slab of 1024 quads ----
  const int b  = blockIdx.x - 1;        // 0 .. 8191
  const int ln = b >> 6;                // l*32+n, 0..127
  const int c  = b & 63;

  // Stage codebook column c: col_s[q] = cb[q][c]; gathers are broadcasts.
  if (tid < P) col_s[tid] = cb[tid * D + c];
  __syncthreads();

  const unsigned* __restrict__ packs = (const unsigned*)idx8 + (ln << 10);
  float* __restrict__ dst = out + ((long)b << 12);     // 4096 floats

  #pragma unroll
  for (int it = 0; it < QPT; ++it) {
    const int hwq = (it << 8) + tid;                   // 0..1023
    const unsigned pack = packs[hwq];
    f32x4 v;
    v.x = col_s[pack & 15];
    v.y = col_s[(pack >> 8) & 15];
    v.z = col_s[(pack >> 16) & 15];
    v.w = col_s[(pack >> 24) & 15];
    __builtin_nontemporal_store(v, (f32x4*)dst + hwq);
  }
}

}  // namespace

extern "C" void kernel_launch(void* const* d_in, const int* in_sizes, int n_in,
                              void* d_out, int out_size, void* d_ws, size_t ws_size,
                              hipStream_t stream) {
  const float* in   = (const float*)d_in[0];
  const float* cb   = (const float*)d_in[1];
  const float* prev = (const float*)d_in[2];
  float* out = (float*)d_out;

  // ws layout: [0, 32KB) loss partials (2048*4 f32), then 512KB idx8.
  float* partial      = (float*)d_ws;
  unsigned char* idx8 = (unsigned char*)d_ws + NBLK_A * NLEV * sizeof(float);

  avq_assign<<<NBLK_A, ABLK, 0, stream>>>(in, cb, partial, idx8);
  // PROBE: B launched twice (idempotent) -> dur_us ≈ base + t_B + gap.
  avq_expand<<<NBLK_B + 1, BBLK, 0, stream>>>(cb, prev, partial, idx8, out);
  avq_expand<<<NBLK_B + 1, BBLK, 0, stream>>>(cb, prev, partial, idx8, out);
}

// Round 11
// 40.013 us; speedup vs baseline: 1.5631x; 1.5631x over previous
//
#include <hip/hip_runtime.h>

// AdaptiveVectorQuantizer on MI355X (gfx950) — split-kernel structure.
// Round-11 (A only): POSP=2 + dwordx2-staged input loads.
//   Probes measured t_A≈12us (vs 5.4us read floor), t_B≈21us (≈write floor).
//   A's three stacked costs: cb-LDS traffic (256 b128/wave at 8 waves/CU),
//   load latency (scalar loads, too few bytes in flight), VALU. POSP=2:
//   halves LDS traffic AND waves (4/CU), loads all 64 channels as dwordx2
//   upfront (32KB/wave in flight -> latency covered). Per-position FMA
//   chains unchanged (c-ascending) -> same numerics.
// B (avq_expand): unchanged (near write floor). Block 0 = loss finalize.

namespace {

typedef float f32x4 __attribute__((ext_vector_type(4)));
typedef float f32x2 __attribute__((ext_vector_type(2)));

constexpr int D      = 64;
constexpr int P      = 16;
constexpr int NLEV   = 4;
constexpr int NPOS   = 32 * 4096;               // 131072 positions
constexpr int ABLK   = 64;                      // 1 wave per A-block
constexpr int POSP   = 2;                       // positions per thread
constexpr int NBLK_A = NPOS / (ABLK * POSP);    // 1024 (4 waves/CU)
constexpr int BBLK   = 256;
constexpr int QPT    = 4;                       // float4-quads per B-thread
constexpr int NQUAD  = NLEV * NPOS * (D / 4);   // 8,388,608
constexpr int NBLK_B = NQUAD / (BBLK * QPT);    // 8192

// ---------------- Kernel A: assignment + loss partials ----------------
__global__ __launch_bounds__(ABLK) void avq_assign(
    const float* __restrict__ in, const float* __restrict__ cb,
    float* __restrict__ partial, unsigned char* __restrict__ idx8)
{
  __shared__ f32x4 cb4_s[P][D / 4];   // reads are wave-broadcasts
  __shared__ float cb2_s[P];

  const int tid = threadIdx.x;
  for (int i = tid; i < P * (D / 4); i += ABLK)
    cb4_s[i >> 4][i & 15] = ((const f32x4*)cb)[i];
  __syncthreads();
  if (tid < P) {
    float s = 0.f;
    #pragma unroll
    for (int j = 0; j < D / 4; ++j) {
      const f32x4 v = cb4_s[tid][j];
      s = fmaf(v.x, v.x, s); s = fmaf(v.y, v.y, s);
      s = fmaf(v.z, v.z, s); s = fmaf(v.w, v.w, s);
    }
    cb2_s[tid] = s;
  }
  __syncthreads();

  // Block covers 128 consecutive positions of one image (32 blocks/image).
  const int n      = blockIdx.x >> 5;
  const int hwbase = (blockIdx.x & 31) << 7;
  const f32x2* __restrict__ src2 =
      (const f32x2*)(in + (n << 18) + hwbase);   // float2 units

  // Stage both positions' 64 channels upfront: 64 dwordx2 loads in flight.
  f32x2 xv[D];
  #pragma unroll
  for (int c = 0; c < D; ++c) xv[c] = src2[(c << 11) + tid];

  float x2a = 0.f, x2b = 0.f;
  #pragma unroll
  for (int c = 0; c < D; ++c) {
    x2a = fmaf(xv[c].x, xv[c].x, x2a);
    x2b = fmaf(xv[c].y, xv[c].y, x2b);
  }

  float dota[P], dotb[P];
  #pragma unroll
  for (int q = 0; q < P; ++q) { dota[q] = 0.f; dotb[q] = 0.f; }

  // One cb read serves both positions; per-position chain c-ascending.
  #pragma unroll
  for (int c4 = 0; c4 < D / 4; ++c4) {
    #pragma unroll
    for (int q = 0; q < P; ++q) {
      const f32x4 cv = cb4_s[q][c4];
      float da = dota[q], db = dotb[q];
      da = fmaf(xv[c4 * 4 + 0].x, cv.x, da);
      da = fmaf(xv[c4 * 4 + 1].x, cv.y, da);
      da = fmaf(xv[c4 * 4 + 2].x, cv.z, da);
      da = fmaf(xv[c4 * 4 + 3].x, cv.w, da);
      db = fmaf(xv[c4 * 4 + 0].y, cv.x, db);
      db = fmaf(xv[c4 * 4 + 1].y, cv.y, db);
      db = fmaf(xv[c4 * 4 + 2].y, cv.z, db);
      db = fmaf(xv[c4 * 4 + 3].y, cv.w, db);
      dota[q] = da; dotb[q] = db;
    }
  }

  float errsum[NLEV];
  #pragma unroll
  for (int l = 0; l < NLEV; ++l) errsum[l] = 0.f;

  const int p0 = (n << 12) + hwbase + 2 * tid;   // positions p0, p0+1

  // Position a (p0): rel = cb^2 - 2*dot; prefix argmins, strict <.
  {
    float rel[P];
    #pragma unroll
    for (int q = 0; q < P; ++q) rel[q] = fmaf(-2.f, dota[q], cb2_s[q]);
    int bi = 0; float bv = rel[0];
    if (rel[1] < bv) { bv = rel[1]; bi = 1; }
    idx8[0 * NPOS + p0] = (unsigned char)bi; errsum[0] += x2a + bv;
    #pragma unroll
    for (int q = 2; q < 4; ++q)  if (rel[q] < bv) { bv = rel[q]; bi = q; }
    idx8[1 * NPOS + p0] = (unsigned char)bi; errsum[1] += x2a + bv;
    #pragma unroll
    for (int q = 4; q < 8; ++q)  if (rel[q] < bv) { bv = rel[q]; bi = q; }
    idx8[2 * NPOS + p0] = (unsigned char)bi; errsum[2] += x2a + bv;
    #pragma unroll
    for (int q = 8; q < 16; ++q) if (rel[q] < bv) { bv = rel[q]; bi = q; }
    idx8[3 * NPOS + p0] = (unsigned char)bi; errsum[3] += x2a + bv;
  }
  // Position b (p0+1).
  {
    float rel[P];
    #pragma unroll
    for (int q = 0; q < P; ++q) rel[q] = fmaf(-2.f, dotb[q], cb2_s[q]);
    int bi = 0; float bv = rel[0];
    if (rel[1] < bv) { bv = rel[1]; bi = 1; }
    idx8[0 * NPOS + p0 + 1] = (unsigned char)bi; errsum[0] += x2b + bv;
    #pragma unroll
    for (int q = 2; q < 4; ++q)  if (rel[q] < bv) { bv = rel[q]; bi = q; }
    idx8[1 * NPOS + p0 + 1] = (unsigned char)bi; errsum[1] += x2b + bv;
    #pragma unroll
    for (int q = 4; q < 8; ++q)  if (rel[q] < bv) { bv = rel[q]; bi = q; }
    idx8[2 * NPOS + p0 + 1] = (unsigned char)bi; errsum[2] += x2b + bv;
    #pragma unroll
    for (int q = 8; q < 16; ++q) if (rel[q] < bv) { bv = rel[q]; bi = q; }
    idx8[3 * NPOS + p0 + 1] = (unsigned char)bi; errsum[3] += x2b + bv;
  }

  // Single-wave block: shuffle-reduce, lane 0 writes the 4 partials.
  #pragma unroll
  for (int l = 0; l < NLEV; ++l) {
    float v = errsum[l];
    #pragma unroll
    for (int off = 32; off > 0; off >>= 1) v += __shfl_down(v, off, 64);
    if (tid == 0) partial[blockIdx.x * NLEV + l] = v;
  }
}

// ---------------- Kernel B: expand + (block 0) finalize ----------------
__device__ inline float block_sum256(float v, float* sbuf, int tid) {
  #pragma unroll
  for (int off = 32; off > 0; off >>= 1) v += __shfl_down(v, off, 64);
  __syncthreads();
  if ((tid & 63) == 0) sbuf[tid >> 6] = v;
  __syncthreads();
  const float r = sbuf[0] + sbuf[1] + sbuf[2] + sbuf[3];
  __syncthreads();
  return r;
}

__global__ __launch_bounds__(BBLK) void avq_expand(
    const float* __restrict__ cb, const float* __restrict__ prev,
    const float* __restrict__ partial, const unsigned char* __restrict__ idx8,
    float* __restrict__ out)
{
  __shared__ float col_s[P];
  __shared__ float sbuf[4];
  const int tid = threadIdx.x;

  if (blockIdx.x == 0) {
    // ---- finalize: losses + codebook passthrough ----
    float* __restrict__ losses = out + NQUAD * 4;      // 33,554,432
    float* __restrict__ cbout  = losses + NLEV;
    for (int i = tid; i < P * D; i += BBLK) cbout[i] = cb[i];

    float s0 = 0.f, s1 = 0.f, s2 = 0.f, s3 = 0.f;
    for (int b = tid; b < NBLK_A; b += BBLK) {
      s0 += partial[b * NLEV + 0];
      s1 += partial[b * NLEV + 1];
      s2 += partial[b * NLEV + 2];
      s3 += partial[b * NLEV + 3];
    }
    float p1 = 0.f, p2 = 0.f, p3 = 0.f;
    for (int e = tid; e < 8 * D; e += BBLK) {
      const float dlt = prev[e] - cb[e];
      const float d2  = dlt * dlt;
      const int   r   = e >> 6;
      if (r < 2) p1 += d2;
      if (r < 4) p2 += d2;
      p3 += d2;
    }
    s0 = block_sum256(s0, sbuf, tid);
    s1 = block_sum256(s1, sbuf, tid);
    s2 = block_sum256(s2, sbuf, tid);
    s3 = block_sum256(s3, sbuf, tid);
    p1 = block_sum256(p1, sbuf, tid);
    p2 = block_sum256(p2, sbuf, tid);
    p3 = block_sum256(p3, sbuf, tid);
    if (tid == 0) {
      const float inv = 1.0f / 8388608.0f;             // 1/(M*D)
      const float ql0 = s0 * inv, ql1 = s1 * inv, ql2 = s2 * inv, ql3 = s3 * inv;
      losses[0] = ql0 + 0.1f * ql0;
      losses[1] = ql1 + 0.1f * ql1 + 1.0f * 0.33f * (p1 * (1.0f / 128.0f));
      losses[2] = ql2 + 2.0f * 0.33f * (p2 * (1.0f / 256.0f));
      losses[3] = ql3 + 3.0f * 0.33f * (p3 * (1.0f / 512.0f));
    }
    return;
  }

  // ---- expansion: block b covers one (l,n,c) slab of 1024 quads ----
  const int b  = blockIdx.x - 1;        // 0 .. 8191
  const int ln = b >> 6;                // l*32+n, 0..127
  const int c  = b & 63;

  // Stage codebook column c: col_s[q] = cb[q][c]; gathers are broadcasts.
  if (tid < P) col_s[tid] = cb[tid * D + c];
  __syncthreads();

  const unsigned* __restrict__ packs = (const unsigned*)idx8 + (ln << 10);
  float* __restrict__ dst = out + ((long)b << 12);     // 4096 floats

  #pragma unroll
  for (int it = 0; it < QPT; ++it) {
    const int hwq = (it << 8) + tid;                   // 0..1023
    const unsigned pack = packs[hwq];
    f32x4 v;
    v.x = col_s[pack & 15];
    v.y = col_s[(pack >> 8) & 15];
    v.z = col_s[(pack >> 16) & 15];
    v.w = col_s[(pack >> 24) & 15];
    __builtin_nontemporal_store(v, (f32x4*)dst + hwq);
  }
}

}  // namespace

extern "C" void kernel_launch(void* const* d_in, const int* in_sizes, int n_in,
                              void* d_out, int out_size, void* d_ws, size_t ws_size,
                              hipStream_t stream) {
  const float* in   = (const float*)d_in[0];
  const float* cb   = (const float*)d_in[1];
  const float* prev = (const float*)d_in[2];
  float* out = (float*)d_out;

  // ws layout: [0, 16KB) loss partials (1024*4 f32), then 512KB idx8.
  float* partial      = (float*)d_ws;
  unsigned char* idx8 = (unsigned char*)d_ws + NBLK_A * NLEV * sizeof(float);

  avq_assign<<<NBLK_A, ABLK, 0, stream>>>(in, cb, partial, idx8);
  avq_expand<<<NBLK_B + 1, BBLK, 0, stream>>>(cb, prev, partial, idx8, out);
}

// Round 12
// 39.853 us; speedup vs baseline: 1.5694x; 1.0040x over previous
//
#include <hip/hip_runtime.h>

// AdaptiveVectorQuantizer on MI355X (gfx950) — split-kernel structure.
// Round-12 (B only, single lever): plain stores instead of nontemporal.
//   Probes: t_A+gap=12.96, t_B+gap=22.52 vs B's 19.2us write floor. The
//   7TB/s fillBuffer anchor uses PLAIN stores; our NT policy flag is the
//   one untested difference on the write path. A is bit-identical to r5
//   (the 40.0us baseline) for clean attribution.
// A (avq_assign): 1 thread/position, reg-staged 64 channel loads, LDS cb.
// B (avq_expand): streaming expand, one (l,n,c) slab per block, codebook
//   column in LDS, 4x16B PLAIN stores/thread. Block 0 = loss finalize.

namespace {

typedef float f32x4 __attribute__((ext_vector_type(4)));

constexpr int D      = 64;
constexpr int P      = 16;
constexpr int NLEV   = 4;
constexpr int NPOS   = 32 * 4096;               // 131072 positions
constexpr int ABLK   = 64;                      // 1 wave per A-block
constexpr int NBLK_A = NPOS / ABLK;             // 2048
constexpr int BBLK   = 256;
constexpr int QPT    = 4;                       // float4-quads per B-thread
constexpr int NQUAD  = NLEV * NPOS * (D / 4);   // 8,388,608
constexpr int NBLK_B = NQUAD / (BBLK * QPT);    // 8192

// ---------------- Kernel A: assignment + loss partials ----------------
__global__ __launch_bounds__(ABLK) void avq_assign(
    const float* __restrict__ in, const float* __restrict__ cb,
    float* __restrict__ partial, unsigned char* __restrict__ idx8)
{
  __shared__ f32x4 cb4_s[P][D / 4];   // reads are wave-broadcasts
  __shared__ float cb2_s[P];

  const int tid = threadIdx.x;
  for (int i = tid; i < P * (D / 4); i += ABLK)
    cb4_s[i >> 4][i & 15] = ((const f32x4*)cb)[i];
  __syncthreads();
  if (tid < P) {
    float s = 0.f;
    #pragma unroll
    for (int j = 0; j < D / 4; ++j) {
      const f32x4 v = cb4_s[tid][j];
      s = fmaf(v.x, v.x, s); s = fmaf(v.y, v.y, s);
      s = fmaf(v.z, v.z, s); s = fmaf(v.w, v.w, s);
    }
    cb2_s[tid] = s;
  }
  __syncthreads();

  const int p  = blockIdx.x * ABLK + tid;
  const int n  = p >> 12;
  const int hw = p & 4095;
  const float* __restrict__ src = in + (n << 18) + hw;   // stride 4096 over c

  // Stage all channel values first: 64 independent global loads in flight.
  float xv[D];
  #pragma unroll
  for (int c = 0; c < D; ++c) xv[c] = src[c << 12];

  float x2 = 0.f;
  #pragma unroll
  for (int c = 0; c < D; ++c) x2 = fmaf(xv[c], xv[c], x2);

  float dot[P];
  #pragma unroll
  for (int q = 0; q < P; ++q) dot[q] = 0.f;

  // Accumulation strictly c-ascending per q (numerics fixed since round 4).
  #pragma unroll
  for (int c4 = 0; c4 < D / 4; ++c4) {
    #pragma unroll
    for (int q = 0; q < P; ++q) {
      const f32x4 cv = cb4_s[q][c4];
      float dq = dot[q];
      dq = fmaf(xv[c4 * 4 + 0], cv.x, dq);
      dq = fmaf(xv[c4 * 4 + 1], cv.y, dq);
      dq = fmaf(xv[c4 * 4 + 2], cv.z, dq);
      dq = fmaf(xv[c4 * 4 + 3], cv.w, dq);
      dot[q] = dq;
    }
  }

  // rel = cb^2 - 2*dot ; x2 is a common per-row offset -> drop for argmin.
  float rel[P];
  #pragma unroll
  for (int q = 0; q < P; ++q) rel[q] = fmaf(-2.f, dot[q], cb2_s[q]);

  // Prefix argmins over nv={2,4,8,16}; strict < = jnp.argmin tie-break.
  float err[NLEV];
  {
    int bi = 0; float bv = rel[0];
    if (rel[1] < bv) { bv = rel[1]; bi = 1; }
    idx8[0 * NPOS + p] = (unsigned char)bi; err[0] = x2 + bv;
    #pragma unroll
    for (int q = 2; q < 4; ++q)  if (rel[q] < bv) { bv = rel[q]; bi = q; }
    idx8[1 * NPOS + p] = (unsigned char)bi; err[1] = x2 + bv;
    #pragma unroll
    for (int q = 4; q < 8; ++q)  if (rel[q] < bv) { bv = rel[q]; bi = q; }
    idx8[2 * NPOS + p] = (unsigned char)bi; err[2] = x2 + bv;
    #pragma unroll
    for (int q = 8; q < 16; ++q) if (rel[q] < bv) { bv = rel[q]; bi = q; }
    idx8[3 * NPOS + p] = (unsigned char)bi; err[3] = x2 + bv;
  }

  // Single-wave block: shuffle-reduce, lane 0 writes the 4 partials.
  #pragma unroll
  for (int l = 0; l < NLEV; ++l) {
    float v = err[l];
    #pragma unroll
    for (int off = 32; off > 0; off >>= 1) v += __shfl_down(v, off, 64);
    if (tid == 0) partial[blockIdx.x * NLEV + l] = v;
  }
}

// ---------------- Kernel B: expand + (block 0) finalize ----------------
__device__ inline float block_sum256(float v, float* sbuf, int tid) {
  #pragma unroll
  for (int off = 32; off > 0; off >>= 1) v += __shfl_down(v, off, 64);
  __syncthreads();
  if ((tid & 63) == 0) sbuf[tid >> 6] = v;
  __syncthreads();
  const float r = sbuf[0] + sbuf[1] + sbuf[2] + sbuf[3];
  __syncthreads();
  return r;
}

__global__ __launch_bounds__(BBLK) void avq_expand(
    const float* __restrict__ cb, const float* __restrict__ prev,
    const float* __restrict__ partial, const unsigned char* __restrict__ idx8,
    float* __restrict__ out)
{
  __shared__ float col_s[P];
  __shared__ float sbuf[4];
  const int tid = threadIdx.x;

  if (blockIdx.x == 0) {
    // ---- finalize: losses + codebook passthrough ----
    float* __restrict__ losses = out + NQUAD * 4;      // 33,554,432
    float* __restrict__ cbout  = losses + NLEV;
    for (int i = tid; i < P * D; i += BBLK) cbout[i] = cb[i];

    float s0 = 0.f, s1 = 0.f, s2 = 0.f, s3 = 0.f;
    for (int b = tid; b < NBLK_A; b += BBLK) {
      s0 += partial[b * NLEV + 0];
      s1 += partial[b * NLEV + 1];
      s2 += partial[b * NLEV + 2];
      s3 += partial[b * NLEV + 3];
    }
    float p1 = 0.f, p2 = 0.f, p3 = 0.f;
    for (int e = tid; e < 8 * D; e += BBLK) {
      const float dlt = prev[e] - cb[e];
      const float d2  = dlt * dlt;
      const int   r   = e >> 6;
      if (r < 2) p1 += d2;
      if (r < 4) p2 += d2;
      p3 += d2;
    }
    s0 = block_sum256(s0, sbuf, tid);
    s1 = block_sum256(s1, sbuf, tid);
    s2 = block_sum256(s2, sbuf, tid);
    s3 = block_sum256(s3, sbuf, tid);
    p1 = block_sum256(p1, sbuf, tid);
    p2 = block_sum256(p2, sbuf, tid);
    p3 = block_sum256(p3, sbuf, tid);
    if (tid == 0) {
      const float inv = 1.0f / 8388608.0f;             // 1/(M*D)
      const float ql0 = s0 * inv, ql1 = s1 * inv, ql2 = s2 * inv, ql3 = s3 * inv;
      losses[0] = ql0 + 0.1f * ql0;
      losses[1] = ql1 + 0.1f * ql1 + 1.0f * 0.33f * (p1 * (1.0f / 128.0f));
      losses[2] = ql2 + 2.0f * 0.33f * (p2 * (1.0f / 256.0f));
      losses[3] = ql3 + 3.0f * 0.33f * (p3 * (1.0f / 512.0f));
    }
    return;
  }

  // ---- expansion: block b covers one (l,n,c) slab of 1024 quads ----
  const int b  = blockIdx.x - 1;        // 0 .. 8191
  const int ln = b >> 6;                // l*32+n, 0..127
  const int c  = b & 63;

  // Stage codebook column c: col_s[q] = cb[q][c]; gathers are broadcasts.
  if (tid < P) col_s[tid] = cb[tid * D + c];
  __syncthreads();

  const unsigned* __restrict__ packs = (const unsigned*)idx8 + (ln << 10);
  f32x4* __restrict__ dst = (f32x4*)(out + ((long)b << 12));  // 4096 floats

  #pragma unroll
  for (int it = 0; it < QPT; ++it) {
    const int hwq = (it << 8) + tid;                   // 0..1023
    const unsigned pack = packs[hwq];
    f32x4 v;
    v.x = col_s[pack & 15];
    v.y = col_s[(pack >> 8) & 15];
    v.z = col_s[(pack >> 16) & 15];
    v.w = col_s[(pack >> 24) & 15];
    dst[hwq] = v;                                      // plain store (no NT)
  }
}

}  // namespace

extern "C" void kernel_launch(void* const* d_in, const int* in_sizes, int n_in,
                              void* d_out, int out_size, void* d_ws, size_t ws_size,
                              hipStream_t stream) {
  const float* in   = (const float*)d_in[0];
  const float* cb   = (const float*)d_in[1];
  const float* prev = (const float*)d_in[2];
  float* out = (float*)d_out;

  // ws layout: [0, 32KB) loss partials (2048*4 f32), then 512KB idx8.
  float* partial      = (float*)d_ws;
  unsigned char* idx8 = (unsigned char*)d_ws + NBLK_A * NLEV * sizeof(float);

  avq_assign<<<NBLK_A, ABLK, 0, stream>>>(in, cb, partial, idx8);
  avq_expand<<<NBLK_B + 1, BBLK, 0, stream>>>(cb, prev, partial, idx8, out);
}

// Round 13
// 39.526 us; speedup vs baseline: 1.5824x; 1.0083x over previous
//
#include <hip/hip_runtime.h>

// AdaptiveVectorQuantizer on MI355X (gfx950) — split-kernel structure.
// Round-13 (B only, single lever): 4x fatter expansion blocks.
//   t_B≈22.5us vs 19.2 floor with 8192 tiny blocks (4KB stores each) —
//   testing WG dispatch/ramp overhead. Now 2048 blocks, each owns 4 full
//   channel planes of one (l,n): packs loaded ONCE per thread (reused
//   across 4 channels), 16 wave-contiguous f32x4 stores. 8192 waves =
//   32/CU full occupancy. A bit-identical to r12/r5 (40.0us baseline).
// A (avq_assign): 1 thread/position, reg-staged 64 channel loads, LDS cb.
// B (avq_expand): block 0 = loss finalize (unchanged).

namespace {

typedef float f32x4 __attribute__((ext_vector_type(4)));

constexpr int D      = 64;
constexpr int P      = 16;
constexpr int NLEV   = 4;
constexpr int NPOS   = 32 * 4096;               // 131072 positions
constexpr int ABLK   = 64;                      // 1 wave per A-block
constexpr int NBLK_A = NPOS / ABLK;             // 2048
constexpr int BBLK   = 256;
constexpr int NQUAD  = NLEV * NPOS * (D / 4);   // 8,388,608
constexpr int NBLK_B = 2048;                    // 4 planes per block

// ---------------- Kernel A: assignment + loss partials ----------------
__global__ __launch_bounds__(ABLK) void avq_assign(
    const float* __restrict__ in, const float* __restrict__ cb,
    float* __restrict__ partial, unsigned char* __restrict__ idx8)
{
  __shared__ f32x4 cb4_s[P][D / 4];   // reads are wave-broadcasts
  __shared__ float cb2_s[P];

  const int tid = threadIdx.x;
  for (int i = tid; i < P * (D / 4); i += ABLK)
    cb4_s[i >> 4][i & 15] = ((const f32x4*)cb)[i];
  __syncthreads();
  if (tid < P) {
    float s = 0.f;
    #pragma unroll
    for (int j = 0; j < D / 4; ++j) {
      const f32x4 v = cb4_s[tid][j];
      s = fmaf(v.x, v.x, s); s = fmaf(v.y, v.y, s);
      s = fmaf(v.z, v.z, s); s = fmaf(v.w, v.w, s);
    }
    cb2_s[tid] = s;
  }
  __syncthreads();

  const int p  = blockIdx.x * ABLK + tid;
  const int n  = p >> 12;
  const int hw = p & 4095;
  const float* __restrict__ src = in + (n << 18) + hw;   // stride 4096 over c

  // Stage all channel values first: 64 independent global loads in flight.
  float xv[D];
  #pragma unroll
  for (int c = 0; c < D; ++c) xv[c] = src[c << 12];

  float x2 = 0.f;
  #pragma unroll
  for (int c = 0; c < D; ++c) x2 = fmaf(xv[c], xv[c], x2);

  float dot[P];
  #pragma unroll
  for (int q = 0; q < P; ++q) dot[q] = 0.f;

  // Accumulation strictly c-ascending per q (numerics fixed since round 4).
  #pragma unroll
  for (int c4 = 0; c4 < D / 4; ++c4) {
    #pragma unroll
    for (int q = 0; q < P; ++q) {
      const f32x4 cv = cb4_s[q][c4];
      float dq = dot[q];
      dq = fmaf(xv[c4 * 4 + 0], cv.x, dq);
      dq = fmaf(xv[c4 * 4 + 1], cv.y, dq);
      dq = fmaf(xv[c4 * 4 + 2], cv.z, dq);
      dq = fmaf(xv[c4 * 4 + 3], cv.w, dq);
      dot[q] = dq;
    }
  }

  // rel = cb^2 - 2*dot ; x2 is a common per-row offset -> drop for argmin.
  float rel[P];
  #pragma unroll
  for (int q = 0; q < P; ++q) rel[q] = fmaf(-2.f, dot[q], cb2_s[q]);

  // Prefix argmins over nv={2,4,8,16}; strict < = jnp.argmin tie-break.
  float err[NLEV];
  {
    int bi = 0; float bv = rel[0];
    if (rel[1] < bv) { bv = rel[1]; bi = 1; }
    idx8[0 * NPOS + p] = (unsigned char)bi; err[0] = x2 + bv;
    #pragma unroll
    for (int q = 2; q < 4; ++q)  if (rel[q] < bv) { bv = rel[q]; bi = q; }
    idx8[1 * NPOS + p] = (unsigned char)bi; err[1] = x2 + bv;
    #pragma unroll
    for (int q = 4; q < 8; ++q)  if (rel[q] < bv) { bv = rel[q]; bi = q; }
    idx8[2 * NPOS + p] = (unsigned char)bi; err[2] = x2 + bv;
    #pragma unroll
    for (int q = 8; q < 16; ++q) if (rel[q] < bv) { bv = rel[q]; bi = q; }
    idx8[3 * NPOS + p] = (unsigned char)bi; err[3] = x2 + bv;
  }

  // Single-wave block: shuffle-reduce, lane 0 writes the 4 partials.
  #pragma unroll
  for (int l = 0; l < NLEV; ++l) {
    float v = err[l];
    #pragma unroll
    for (int off = 32; off > 0; off >>= 1) v += __shfl_down(v, off, 64);
    if (tid == 0) partial[blockIdx.x * NLEV + l] = v;
  }
}

// ---------------- Kernel B: expand + (block 0) finalize ----------------
__device__ inline float block_sum256(float v, float* sbuf, int tid) {
  #pragma unroll
  for (int off = 32; off > 0; off >>= 1) v += __shfl_down(v, off, 64);
  __syncthreads();
  if ((tid & 63) == 0) sbuf[tid >> 6] = v;
  __syncthreads();
  const float r = sbuf[0] + sbuf[1] + sbuf[2] + sbuf[3];
  __syncthreads();
  return r;
}

__global__ __launch_bounds__(BBLK) void avq_expand(
    const float* __restrict__ cb, const float* __restrict__ prev,
    const float* __restrict__ partial, const unsigned char* __restrict__ idx8,
    float* __restrict__ out)
{
  __shared__ float col_s[4 * P];   // col_s[c_local*16+q] = cb[q][cbase+c_local]
  __shared__ float sbuf[4];
  const int tid = threadIdx.x;

  if (blockIdx.x == 0) {
    // ---- finalize: losses + codebook passthrough ----
    float* __restrict__ losses = out + NQUAD * 4;      // 33,554,432
    float* __restrict__ cbout  = losses + NLEV;
    for (int i = tid; i < P * D; i += BBLK) cbout[i] = cb[i];

    float s0 = 0.f, s1 = 0.f, s2 = 0.f, s3 = 0.f;
    for (int b = tid; b < NBLK_A; b += BBLK) {
      s0 += partial[b * NLEV + 0];
      s1 += partial[b * NLEV + 1];
      s2 += partial[b * NLEV + 2];
      s3 += partial[b * NLEV + 3];
    }
    float p1 = 0.f, p2 = 0.f, p3 = 0.f;
    for (int e = tid; e < 8 * D; e += BBLK) {
      const float dlt = prev[e] - cb[e];
      const float d2  = dlt * dlt;
      const int   r   = e >> 6;
      if (r < 2) p1 += d2;
      if (r < 4) p2 += d2;
      p3 += d2;
    }
    s0 = block_sum256(s0, sbuf, tid);
    s1 = block_sum256(s1, sbuf, tid);
    s2 = block_sum256(s2, sbuf, tid);
    s3 = block_sum256(s3, sbuf, tid);
    p1 = block_sum256(p1, sbuf, tid);
    p2 = block_sum256(p2, sbuf, tid);
    p3 = block_sum256(p3, sbuf, tid);
    if (tid == 0) {
      const float inv = 1.0f / 8388608.0f;             // 1/(M*D)
      const float ql0 = s0 * inv, ql1 = s1 * inv, ql2 = s2 * inv, ql3 = s3 * inv;
      losses[0] = ql0 + 0.1f * ql0;
      losses[1] = ql1 + 0.1f * ql1 + 1.0f * 0.33f * (p1 * (1.0f / 128.0f));
      losses[2] = ql2 + 2.0f * 0.33f * (p2 * (1.0f / 256.0f));
      losses[3] = ql3 + 3.0f * 0.33f * (p3 * (1.0f / 512.0f));
    }
    return;
  }

  // ---- expansion: block b owns 4 channel planes of one (l,n) ----
  const int b    = blockIdx.x - 1;      // 0 .. 2047
  const int l    = b >> 9;              // 0..3
  const int n    = (b >> 4) & 31;       // 0..31
  const int c4g  = b & 15;              // channel group: c = c4g*4 + c_local

  // Stage 4 codebook columns: col_s[c_local*16+q] = cb[q][c4g*4+c_local].
  if (tid < 4 * P)
    col_s[tid] = cb[(tid & 15) * D + (c4g << 2) + (tid >> 4)];
  __syncthreads();

  // 4 idx packs per thread, loaded once, reused for all 4 channels.
  const unsigned* __restrict__ packs =
      (const unsigned*)idx8 + (l << 15) + (n << 10);
  unsigned pk[4];
  #pragma unroll
  for (int h = 0; h < 4; ++h) pk[h] = packs[(h << 8) + tid];

  f32x4* __restrict__ outq = (f32x4*)out;
  const int plane0 = (l << 11) + (n << 6) + (c4g << 2);   // plane index

  #pragma unroll
  for (int cl = 0; cl < 4; ++cl) {
    const float* __restrict__ col = col_s + (cl << 4);
    const int qbase = ((plane0 + cl) << 10) + tid;
    #pragma unroll
    for (int h = 0; h < 4; ++h) {
      const unsigned pack = pk[h];
      f32x4 v;
      v.x = col[pack & 15];
      v.y = col[(pack >> 8) & 15];
      v.z = col[(pack >> 16) & 15];
      v.w = col[(pack >> 24) & 15];
      outq[qbase + (h << 8)] = v;
    }
  }
}

}  // namespace

extern "C" void kernel_launch(void* const* d_in, const int* in_sizes, int n_in,
                              void* d_out, int out_size, void* d_ws, size_t ws_size,
                              hipStream_t stream) {
  const float* in   = (const float*)d_in[0];
  const float* cb   = (const float*)d_in[1];
  const float* prev = (const float*)d_in[2];
  float* out = (float*)d_out;

  // ws layout: [0, 32KB) loss partials (2048*4 f32), then 512KB idx8.
  float* partial      = (float*)d_ws;
  unsigned char* idx8 = (unsigned char*)d_ws + NBLK_A * NLEV * sizeof(float);

  avq_assign<<<NBLK_A, ABLK, 0, stream>>>(in, cb, partial, idx8);
  avq_expand<<<NBLK_B + 1, BBLK, 0, stream>>>(cb, prev, partial, idx8, out);
}